// Round 1
// baseline (278.322 us; speedup 1.0000x reference)
//
#include <hip/hip_runtime.h>
#include <hip/hip_bf16.h>

#define HH   56
#define WW_  56
#define CIN  128
#define OCH  256
#define KDIM 1152            // 9*128
#define NPIX (32*56*56)      // 100352

#define BM 128
#define BN 128
#define THREADS 256

typedef __attribute__((ext_vector_type(8))) short bf16x8;
typedef __attribute__((ext_vector_type(4))) float f32x4;

__device__ __forceinline__ unsigned short f2bf(float f) {
  union { float f; unsigned u; } v; v.f = f;
  unsigned r = v.u + 0x7FFF + ((v.u >> 16) & 1);   // round-to-nearest-even
  return (unsigned short)(r >> 16);
}

__global__ __launch_bounds__(THREADS) void conv3x3_mfma(
    const float* __restrict__ x, const float* __restrict__ w,
    const float* __restrict__ bias, float* __restrict__ out)
{
  // 128 rows x 32 bf16 = 64 B/row, XOR-swizzled
  __shared__ alignas(16) unsigned char As[BM * 64];
  __shared__ alignas(16) unsigned char Bs[BN * 64];

  const int tid = threadIdx.x;
  const int mt = blockIdx.x >> 1;
  const int nt = blockIdx.x & 1;
  const int m0 = mt * BM;
  const int n0 = nt * BN;

  // ---- staging coords: 2 threads per LDS row, 16 floats each ----
  const int srow = tid >> 1;          // 0..127
  const int soff = (tid & 1) * 16;    // element offset within 32-wide K-chunk

  const int p   = m0 + srow;          // output pixel for A row
  const int pb  = p / (HH * WW_);
  const int phw = p - pb * (HH * WW_);
  const int ph  = phw / WW_;
  const int pw  = phw - ph * WW_;

  const float* xrow = x + ((size_t)((pb * HH + ph) * WW_ + pw)) * CIN + soff;
  const float* wrow = w + (size_t)(n0 + srow) * KDIM + soff;

  // swizzled LDS write offsets (two 16B writes per thread per tile)
  const int sw0 = (srow * 64 + soff * 2)      ^ ((srow & 7) << 4);
  const int sw1 = (srow * 64 + soff * 2 + 16) ^ ((srow & 7) << 4);

  // ---- MFMA fragment coords ----
  const int lane = tid & 63;
  const int wv = tid >> 6;            // 4 waves: 2x2 over 64x64 sub-tiles
  const int wm = (wv >> 1) * 64;
  const int wn = (wv & 1) * 64;
  const int fr = lane & 15;           // A-row / B-col within fragment
  const int fq = lane >> 4;           // K quarter (8 bf16 each)

  int aoff[4], boff[4];
#pragma unroll
  for (int i = 0; i < 4; ++i) {
    const int r = wm + i * 16 + fr;
    aoff[i] = (r * 64 + fq * 16) ^ ((r & 7) << 4);
    const int c = wn + i * 16 + fr;
    boff[i] = (c * 64 + fq * 16) ^ ((c & 7) << 4);
  }

  f32x4 acc[4][4];
  const f32x4 zero4 = {0.f, 0.f, 0.f, 0.f};
#pragma unroll
  for (int i = 0; i < 4; ++i)
#pragma unroll
    for (int j = 0; j < 4; ++j) acc[i][j] = zero4;

#pragma unroll 1
  for (int kpos = 0; kpos < 9; ++kpos) {
    const int ky = kpos / 3;
    const int kx = kpos - ky * 3;
    const int ih = ph + ky - 1;
    const int iw = pw + kx - 1;
    const bool valid = ((unsigned)ih < (unsigned)HH) & ((unsigned)iw < (unsigned)WW_);
    const float* asrc = xrow + ((ky - 1) * WW_ + (kx - 1)) * CIN;
    const float* bsrc = wrow + kpos * CIN;

#pragma unroll 1
    for (int kc = 0; kc < 4; ++kc) {
      float4 a0, a1, a2, a3;
      if (valid) {
        const float4* s = (const float4*)(asrc + kc * 32);
        a0 = s[0]; a1 = s[1]; a2 = s[2]; a3 = s[3];
      } else {
        a0 = make_float4(0.f, 0.f, 0.f, 0.f);
        a1 = a0; a2 = a0; a3 = a0;
      }
      const float4* t = (const float4*)(bsrc + kc * 32);
      const float4 b0 = t[0], b1 = t[1], b2 = t[2], b3 = t[3];

      __syncthreads();   // previous iteration's fragment reads complete

      union { bf16x8 v; unsigned short u[8]; } pA0, pA1, pB0, pB1;
      pA0.u[0] = f2bf(a0.x); pA0.u[1] = f2bf(a0.y); pA0.u[2] = f2bf(a0.z); pA0.u[3] = f2bf(a0.w);
      pA0.u[4] = f2bf(a1.x); pA0.u[5] = f2bf(a1.y); pA0.u[6] = f2bf(a1.z); pA0.u[7] = f2bf(a1.w);
      pA1.u[0] = f2bf(a2.x); pA1.u[1] = f2bf(a2.y); pA1.u[2] = f2bf(a2.z); pA1.u[3] = f2bf(a2.w);
      pA1.u[4] = f2bf(a3.x); pA1.u[5] = f2bf(a3.y); pA1.u[6] = f2bf(a3.z); pA1.u[7] = f2bf(a3.w);
      pB0.u[0] = f2bf(b0.x); pB0.u[1] = f2bf(b0.y); pB0.u[2] = f2bf(b0.z); pB0.u[3] = f2bf(b0.w);
      pB0.u[4] = f2bf(b1.x); pB0.u[5] = f2bf(b1.y); pB0.u[6] = f2bf(b1.z); pB0.u[7] = f2bf(b1.w);
      pB1.u[0] = f2bf(b2.x); pB1.u[1] = f2bf(b2.y); pB1.u[2] = f2bf(b2.z); pB1.u[3] = f2bf(b2.w);
      pB1.u[4] = f2bf(b3.x); pB1.u[5] = f2bf(b3.y); pB1.u[6] = f2bf(b3.z); pB1.u[7] = f2bf(b3.w);

      *(bf16x8*)(As + sw0) = pA0.v;
      *(bf16x8*)(As + sw1) = pA1.v;
      *(bf16x8*)(Bs + sw0) = pB0.v;
      *(bf16x8*)(Bs + sw1) = pB1.v;

      __syncthreads();

      bf16x8 af[4], bfr[4];
#pragma unroll
      for (int i = 0; i < 4; ++i) af[i]  = *(const bf16x8*)(As + aoff[i]);
#pragma unroll
      for (int j = 0; j < 4; ++j) bfr[j] = *(const bf16x8*)(Bs + boff[j]);
#pragma unroll
      for (int i = 0; i < 4; ++i)
#pragma unroll
        for (int j = 0; j < 4; ++j)
          acc[i][j] = __builtin_amdgcn_mfma_f32_16x16x32_bf16(af[i], bfr[j], acc[i][j], 0, 0, 0);
    }
  }

  // ---- epilogue: + bias, write fp32 NHWC ----
  float bv[4];
#pragma unroll
  for (int j = 0; j < 4; ++j) bv[j] = bias[n0 + wn + j * 16 + fr];

#pragma unroll
  for (int mi = 0; mi < 4; ++mi) {
#pragma unroll
    for (int j = 0; j < 4; ++j) {
      const int prow = m0 + wm + mi * 16 + fq * 4 + j;   // output pixel
      float* orow = out + (size_t)prow * OCH + n0 + wn + fr;
#pragma unroll
      for (int ni = 0; ni < 4; ++ni) {
        orow[ni * 16] = acc[mi][ni][j] + bv[ni];
      }
    }
  }
}

extern "C" void kernel_launch(void* const* d_in, const int* in_sizes, int n_in,
                              void* d_out, int out_size, void* d_ws, size_t ws_size,
                              hipStream_t stream) {
  (void)in_sizes; (void)n_in; (void)out_size; (void)d_ws; (void)ws_size;
  const float* x = (const float*)d_in[0];
  const float* w = (const float*)d_in[1];
  const float* b = (const float*)d_in[2];
  float* out = (float*)d_out;

  const int grid = (NPIX / BM) * (OCH / BN);   // 784 * 2 = 1568
  conv3x3_mfma<<<dim3(grid), dim3(THREADS), 0, stream>>>(x, w, b, out);
}

// Round 2
// 204.669 us; speedup vs baseline: 1.3599x; 1.3599x over previous
//
#include <hip/hip_runtime.h>
#include <hip/hip_bf16.h>

#define HH   56
#define WW_  56
#define CIN  128
#define OCH  256
#define NPIX (32*56*56)          // 100352
#define NX   (NPIX*CIN)          // 12845056 x elems
#define NW   (OCH*9*CIN)         // 294912 w elems
#define XB_BYTES ((size_t)NX*2)  // 25690112
#define WB_BYTES ((size_t)NW*2)  // 589824
#define ZP_OFF   (XB_BYTES + WB_BYTES)
#define WS_NEEDED (ZP_OFF + 256)

#define BM 128
#define BN 128
#define THREADS 256

typedef __attribute__((ext_vector_type(8))) short bf16x8;
typedef __attribute__((ext_vector_type(4))) float f32x4;
typedef __attribute__((address_space(1))) void v_g;
typedef __attribute__((address_space(3))) void v_l;

__device__ __forceinline__ unsigned short f2bf(float f) {
  union { float f; unsigned u; } v; v.f = f;
  unsigned r = v.u + 0x7FFF + ((v.u >> 16) & 1);   // RNE
  return (unsigned short)(r >> 16);
}

// ---------------- convert kernel: fp32 -> bf16 into ws ----------------
__global__ __launch_bounds__(256) void convert_kern(
    const float* __restrict__ x, const float* __restrict__ w,
    char* __restrict__ ws)
{
  if (blockIdx.x == 0 && threadIdx.x < 64)
    ((float*)(ws + ZP_OFF))[threadIdx.x] = 0.f;   // zero page for OOB lanes

  unsigned short* out = (unsigned short*)ws;      // xb then wb contiguous
  const int NT8 = (NX + NW) / 8;
  for (int i = blockIdx.x * blockDim.x + threadIdx.x; i < NT8;
       i += gridDim.x * blockDim.x) {
    const int e = i * 8;
    const float* src = (e < NX) ? (x + e) : (w + (e - NX));
    const float4 a = ((const float4*)src)[0];
    const float4 b = ((const float4*)src)[1];
    union { bf16x8 v; unsigned short u[8]; } p;
    p.u[0] = f2bf(a.x); p.u[1] = f2bf(a.y); p.u[2] = f2bf(a.z); p.u[3] = f2bf(a.w);
    p.u[4] = f2bf(b.x); p.u[5] = f2bf(b.y); p.u[6] = f2bf(b.z); p.u[7] = f2bf(b.w);
    *(bf16x8*)(out + e) = p.v;
  }
}

// ---------------- main GEMM: bf16 MFMA, global_load_lds, dbuf ----------------
// LDS tile rows are 128 B (64 bf16); swizzle: inner ^= (row&7)<<4.
// global_load_lds writes linearly, so the SOURCE lane->chunk map is the
// inverse (same) permutation: chunk = (lane&7) ^ (row&7).
__global__ __launch_bounds__(THREADS, 2) void conv_gemm(
    const char* __restrict__ ws, const float* __restrict__ bias,
    float* __restrict__ out)
{
  __shared__ char lds[2][32768];   // [buf][ A 16KB | B 16KB ]

  const char* xb = ws;
  const char* wb = ws + XB_BYTES;
  const char* zp = ws + ZP_OFF;

  const int tid  = threadIdx.x;
  const int lane = tid & 63;
  const int wv   = tid >> 6;
  const int m0   = (blockIdx.x >> 1) * BM;
  const int n0   = (blockIdx.x & 1) * BN;

  // ---- staging precompute: wave wv stages rows [wv*32, wv*32+32) of A and B,
  //      4 calls x 8 rows, lane covers row c*8+(lane>>3), 16B chunk (lane&7)^swz
  int pixA[4]; int phA_[4]; int pwA_[4]; int chkA[4]; const char* bsrcB[4];
#pragma unroll
  for (int c = 0; c < 4; ++c) {
    const int rloc  = wv * 32 + c * 8 + (lane >> 3);
    const int chunk = ((lane & 7) ^ (rloc & 7)) * 16;
    chkA[c] = chunk;
    const int p   = m0 + rloc;
    const int pb  = p / (HH * WW_);
    const int phw = p - pb * (HH * WW_);
    phA_[c] = phw / WW_;
    pwA_[c] = phw - phA_[c] * WW_;
    pixA[c] = p;                                   // = pb*3136 + ph*56 + pw
    bsrcB[c] = wb + (size_t)(n0 + rloc) * (9 * CIN * 2) + chunk;
  }

  // ---- MFMA fragment coords ----
  const int fr = lane & 15;
  const int fq = lane >> 4;
  const int wm = (wv >> 1) * 64;
  const int wn = (wv & 1) * 64;

  int aoff[2][4], boff[2][4];
#pragma unroll
  for (int ks = 0; ks < 2; ++ks)
#pragma unroll
    for (int i = 0; i < 4; ++i) {
      const int r = wm + i * 16 + fr;
      aoff[ks][i] = r * 128 + ((ks * 64 + fq * 16) ^ ((r & 7) << 4));
      const int c = wn + i * 16 + fr;
      boff[ks][i] = 16384 + c * 128 + ((ks * 64 + fq * 16) ^ ((c & 7) << 4));
    }

  f32x4 acc[4][4];
  const f32x4 zero4 = {0.f, 0.f, 0.f, 0.f};
#pragma unroll
  for (int i = 0; i < 4; ++i)
#pragma unroll
    for (int j = 0; j < 4; ++j) acc[i][j] = zero4;

#define STAGE(tt, bb) do {                                                   \
    const int kpos_ = (tt) >> 1, kc_ = (tt) & 1;                             \
    const int ky_ = kpos_ / 3;                                               \
    const int dy_ = ky_ - 1, dx_ = kpos_ - ky_ * 3 - 1;                      \
    _Pragma("unroll")                                                        \
    for (int c = 0; c < 4; ++c) {                                            \
      const int ih_ = phA_[c] + dy_, iw_ = pwA_[c] + dx_;                    \
      const bool v_ = ((unsigned)ih_ < (unsigned)HH) &                       \
                      ((unsigned)iw_ < (unsigned)WW_);                       \
      const char* ga_ = v_ ? (xb + (size_t)(pixA[c] + dy_ * WW_ + dx_) * 256 \
                                 + kc_ * 128 + chkA[c])                      \
                           : (zp + chkA[c]);                                 \
      __builtin_amdgcn_global_load_lds((const v_g*)ga_,                      \
          (v_l*)(&lds[bb][0] + wv * 4096 + c * 1024), 16, 0, 0);             \
      const char* gb_ = bsrcB[c] + (tt) * 128;                               \
      __builtin_amdgcn_global_load_lds((const v_g*)gb_,                      \
          (v_l*)(&lds[bb][16384] + wv * 4096 + c * 1024), 16, 0, 0);         \
    }                                                                        \
  } while (0)

  STAGE(0, 0);
  __syncthreads();

#pragma unroll 2
  for (int t = 0; t < 18; ++t) {
    if (t < 17) STAGE(t + 1, (t + 1) & 1);

    const char* base = &lds[t & 1][0];
    bf16x8 A[2][4], Bv[2][4];
#pragma unroll
    for (int ks = 0; ks < 2; ++ks)
#pragma unroll
      for (int i = 0; i < 4; ++i) {
        A[ks][i]  = *(const bf16x8*)(base + aoff[ks][i]);
        Bv[ks][i] = *(const bf16x8*)(base + boff[ks][i]);
      }
#pragma unroll
    for (int ks = 0; ks < 2; ++ks)
#pragma unroll
      for (int mi = 0; mi < 4; ++mi)
#pragma unroll
        for (int nj = 0; nj < 4; ++nj)
          acc[mi][nj] = __builtin_amdgcn_mfma_f32_16x16x32_bf16(
              A[ks][mi], Bv[ks][nj], acc[mi][nj], 0, 0, 0);

    __syncthreads();   // drains vmcnt (staging) + covers buf reuse
  }
#undef STAGE

  // ---- epilogue: + bias, fp32 NHWC ----
  float bv[4];
#pragma unroll
  for (int j = 0; j < 4; ++j) bv[j] = bias[n0 + wn + j * 16 + fr];

#pragma unroll
  for (int mi = 0; mi < 4; ++mi) {
#pragma unroll
    for (int j = 0; j < 4; ++j) {
      const int prow = m0 + wm + mi * 16 + fq * 4 + j;
      float* orow = out + (size_t)prow * OCH + n0 + wn + fr;
#pragma unroll
      for (int ni = 0; ni < 4; ++ni)
        orow[ni * 16] = acc[mi][ni][j] + bv[ni];
    }
  }
}

// ---------------- fallback (round-1 kernel, used if ws too small) ----------------
__global__ __launch_bounds__(THREADS) void conv3x3_mfma_fb(
    const float* __restrict__ x, const float* __restrict__ w,
    const float* __restrict__ bias, float* __restrict__ out)
{
  __shared__ alignas(16) unsigned char As[BM * 64];
  __shared__ alignas(16) unsigned char Bs[BN * 64];

  const int tid = threadIdx.x;
  const int m0 = (blockIdx.x >> 1) * BM;
  const int n0 = (blockIdx.x & 1) * BN;

  const int srow = tid >> 1;
  const int soff = (tid & 1) * 16;

  const int p   = m0 + srow;
  const int pb  = p / (HH * WW_);
  const int phw = p - pb * (HH * WW_);
  const int ph  = phw / WW_;
  const int pw  = phw - ph * WW_;

  const float* xrow = x + ((size_t)((pb * HH + ph) * WW_ + pw)) * CIN + soff;
  const float* wrow = w + (size_t)(n0 + srow) * (9 * CIN) + soff;

  const int sw0 = (srow * 64 + soff * 2)      ^ ((srow & 7) << 4);
  const int sw1 = (srow * 64 + soff * 2 + 16) ^ ((srow & 7) << 4);

  const int lane = tid & 63;
  const int wv = tid >> 6;
  const int wm = (wv >> 1) * 64;
  const int wn = (wv & 1) * 64;
  const int fr = lane & 15;
  const int fq = lane >> 4;

  int aoff[4], boff[4];
#pragma unroll
  for (int i = 0; i < 4; ++i) {
    const int r = wm + i * 16 + fr;
    aoff[i] = (r * 64 + fq * 16) ^ ((r & 7) << 4);
    const int c = wn + i * 16 + fr;
    boff[i] = (c * 64 + fq * 16) ^ ((c & 7) << 4);
  }

  f32x4 acc[4][4];
  const f32x4 zero4 = {0.f, 0.f, 0.f, 0.f};
#pragma unroll
  for (int i = 0; i < 4; ++i)
#pragma unroll
    for (int j = 0; j < 4; ++j) acc[i][j] = zero4;

#pragma unroll 1
  for (int kpos = 0; kpos < 9; ++kpos) {
    const int ky = kpos / 3;
    const int kx = kpos - ky * 3;
    const int ih = ph + ky - 1;
    const int iw = pw + kx - 1;
    const bool valid = ((unsigned)ih < (unsigned)HH) & ((unsigned)iw < (unsigned)WW_);
    const float* asrc = xrow + ((ky - 1) * WW_ + (kx - 1)) * CIN;
    const float* bsrc = wrow + kpos * CIN;

#pragma unroll 1
    for (int kc = 0; kc < 4; ++kc) {
      float4 a0, a1, a2, a3;
      if (valid) {
        const float4* s = (const float4*)(asrc + kc * 32);
        a0 = s[0]; a1 = s[1]; a2 = s[2]; a3 = s[3];
      } else {
        a0 = make_float4(0.f, 0.f, 0.f, 0.f);
        a1 = a0; a2 = a0; a3 = a0;
      }
      const float4* tql = (const float4*)(bsrc + kc * 32);
      const float4 b0 = tql[0], b1 = tql[1], b2 = tql[2], b3 = tql[3];

      __syncthreads();

      union { bf16x8 v; unsigned short u[8]; } pA0, pA1, pB0, pB1;
      pA0.u[0] = f2bf(a0.x); pA0.u[1] = f2bf(a0.y); pA0.u[2] = f2bf(a0.z); pA0.u[3] = f2bf(a0.w);
      pA0.u[4] = f2bf(a1.x); pA0.u[5] = f2bf(a1.y); pA0.u[6] = f2bf(a1.z); pA0.u[7] = f2bf(a1.w);
      pA1.u[0] = f2bf(a2.x); pA1.u[1] = f2bf(a2.y); pA1.u[2] = f2bf(a2.z); pA1.u[3] = f2bf(a2.w);
      pA1.u[4] = f2bf(a3.x); pA1.u[5] = f2bf(a3.y); pA1.u[6] = f2bf(a3.z); pA1.u[7] = f2bf(a3.w);
      pB0.u[0] = f2bf(b0.x); pB0.u[1] = f2bf(b0.y); pB0.u[2] = f2bf(b0.z); pB0.u[3] = f2bf(b0.w);
      pB0.u[4] = f2bf(b1.x); pB0.u[5] = f2bf(b1.y); pB0.u[6] = f2bf(b1.z); pB0.u[7] = f2bf(b1.w);
      pB1.u[0] = f2bf(b2.x); pB1.u[1] = f2bf(b2.y); pB1.u[2] = f2bf(b2.z); pB1.u[3] = f2bf(b2.w);
      pB1.u[4] = f2bf(b3.x); pB1.u[5] = f2bf(b3.y); pB1.u[6] = f2bf(b3.z); pB1.u[7] = f2bf(b3.w);

      *(bf16x8*)(As + sw0) = pA0.v;
      *(bf16x8*)(As + sw1) = pA1.v;
      *(bf16x8*)(Bs + sw0) = pB0.v;
      *(bf16x8*)(Bs + sw1) = pB1.v;

      __syncthreads();

      bf16x8 af[4], bfr[4];
#pragma unroll
      for (int i = 0; i < 4; ++i) af[i]  = *(const bf16x8*)(As + aoff[i]);
#pragma unroll
      for (int j = 0; j < 4; ++j) bfr[j] = *(const bf16x8*)(Bs + boff[j]);
#pragma unroll
      for (int i = 0; i < 4; ++i)
#pragma unroll
        for (int j = 0; j < 4; ++j)
          acc[i][j] = __builtin_amdgcn_mfma_f32_16x16x32_bf16(af[i], bfr[j], acc[i][j], 0, 0, 0);
    }
  }

  float bv[4];
#pragma unroll
  for (int j = 0; j < 4; ++j) bv[j] = bias[n0 + wn + j * 16 + fr];

#pragma unroll
  for (int mi = 0; mi < 4; ++mi) {
#pragma unroll
    for (int j = 0; j < 4; ++j) {
      const int prow = m0 + wm + mi * 16 + fq * 4 + j;
      float* orow = out + (size_t)prow * OCH + n0 + wn + fr;
#pragma unroll
      for (int ni = 0; ni < 4; ++ni)
        orow[ni * 16] = acc[mi][ni][j] + bv[ni];
    }
  }
}

extern "C" void kernel_launch(void* const* d_in, const int* in_sizes, int n_in,
                              void* d_out, int out_size, void* d_ws, size_t ws_size,
                              hipStream_t stream) {
  (void)in_sizes; (void)n_in; (void)out_size;
  const float* x = (const float*)d_in[0];
  const float* w = (const float*)d_in[1];
  const float* b = (const float*)d_in[2];
  float* out = (float*)d_out;

  if (ws_size >= WS_NEEDED) {
    convert_kern<<<dim3(2048), dim3(256), 0, stream>>>(x, w, (char*)d_ws);
    const int grid = (NPIX / BM) * (OCH / BN);   // 1568
    conv_gemm<<<dim3(grid), dim3(THREADS), 0, stream>>>((const char*)d_ws, b, out);
  } else {
    const int grid = (NPIX / BM) * (OCH / BN);
    conv3x3_mfma_fb<<<dim3(grid), dim3(THREADS), 0, stream>>>(x, w, b, out);
  }
}